// Round 1
// baseline (197.882 us; speedup 1.0000x reference)
//
#include <hip/hip_runtime.h>

// ConvByMoveLayer: out[b,f,o] = sum_m sum_c x[b, mask[m,f], c] * W[m,c,o] + bias[f,o]
// B=128, F=4096, C=32, O=32, M=9.
//
// Design (round 1):
//   Gather-GEMM view: Out[B*F, 32] = G[B*F, 288] @ Wstack[288, 32], Wstack constant.
//   Pass 1: x fp32 -> fp16 in ws (streaming 96 MB); block 0 also builds Wstack in
//           MFMA B-fragment order (wf[t][lane][8], t = K-slice of 16).
//   Pass 2: wave = 32 batches x 1 field = 32x32 tile, 18x v_mfma_f32_32x32x16_f16.
//           Block = 4 waves (all 128 b) x FPB fields; mask in LDS; Wstack frags in
//           72 VGPRs loaded once per wave.
//   fp32 fallback kernel if ws_size too small.

#define B_ 128
#define F_ 4096
#define C_ 32
#define O_ 32
#define M_ 9
#define T_ 18   // number of K=16 MFMA slices (M_*C_/16)
#define FPB 4   // fields per block

typedef _Float16 halfx8 __attribute__((ext_vector_type(8)));
typedef float floatx16 __attribute__((ext_vector_type(16)));

// ---------------- Pass 1: convert x to fp16, build W fragments ----------------
__global__ __launch_bounds__(256) void pass1_convert(
    const float* __restrict__ x, const float* __restrict__ coeffs,
    _Float16* __restrict__ xh, _Float16* __restrict__ wf)
{
    int gid  = blockIdx.x * 256 + threadIdx.x;
    int base = gid * 8;                       // B_*F_*C_ is an exact multiple of 8*256
    const float4* p = reinterpret_cast<const float4*>(x + base);
    float4 v0 = p[0];
    float4 v1 = p[1];
    halfx8 r;
    r[0] = (_Float16)v0.x; r[1] = (_Float16)v0.y;
    r[2] = (_Float16)v0.z; r[3] = (_Float16)v0.w;
    r[4] = (_Float16)v1.x; r[5] = (_Float16)v1.y;
    r[6] = (_Float16)v1.z; r[7] = (_Float16)v1.w;
    *reinterpret_cast<halfx8*>(xh + base) = r;

    // Block 0 additionally builds the B-fragment-ordered weight stack:
    // wf[t][lane][j] = W[m = t>>1][c = 16*(t&1) + 8*(lane>>5) + j][o = lane&31]
    if (blockIdx.x == 0) {
        for (int id = threadIdx.x; id < T_ * 64; id += 256) {
            int t  = id >> 6;
            int L  = id & 63;
            int m  = t >> 1;
            int cb = 16 * (t & 1) + 8 * (L >> 5);
            int o  = L & 31;
            halfx8 w;
#pragma unroll
            for (int j = 0; j < 8; ++j)
                w[j] = (_Float16)coeffs[(m * C_ + cb + j) * O_ + o];
            *reinterpret_cast<halfx8*>(wf + id * 8) = w;
        }
    }
}

// ---------------- Pass 2: gather + MFMA GEMM ----------------
__global__ __launch_bounds__(256) void pass2_gemm(
    const _Float16* __restrict__ xh, const _Float16* __restrict__ wf,
    const int* __restrict__ mask, const float* __restrict__ biases,
    float* __restrict__ out)
{
    __shared__ int smask[M_][FPB];
    const int f0  = blockIdx.x * FPB;
    const int tid = threadIdx.x;
    if (tid < M_ * FPB) {
        int m  = tid / FPB;
        int fi = tid % FPB;
        smask[m][fi] = mask[m * F_ + f0 + fi];
    }
    __syncthreads();

    const int lane  = tid & 63;
    const int wave  = tid >> 6;     // 0..3 -> batch quarter
    const int r32   = lane & 31;
    const int h     = lane >> 5;    // K-half selector for A/B fragments
    const int bbase = wave * 32;

    // Load all 18 B-fragments once per wave (hot 18 KB, L2-resident).
    halfx8 bw[T_];
    const halfx8* wfv = reinterpret_cast<const halfx8*>(wf);
#pragma unroll
    for (int t = 0; t < T_; ++t) bw[t] = wfv[t * 64 + lane];

    // A-fragment base: row of tile = batch (lane&31); +8h = K-half within slice.
    const _Float16* xrow = xh + (size_t)(bbase + r32) * (F_ * C_) + 8 * h;

    for (int fi = 0; fi < FPB; ++fi) {
        const int f = f0 + fi;
        floatx16 acc;
#pragma unroll
        for (int i = 0; i < 16; ++i) acc[i] = 0.0f;
        float bias = biases[f * O_ + r32];
#pragma unroll
        for (int m = 0; m < M_; ++m) {
            const _Float16* rp = xrow + smask[m][fi] * C_;
            halfx8 a0 = *reinterpret_cast<const halfx8*>(rp);       // c = 8h..8h+7
            halfx8 a1 = *reinterpret_cast<const halfx8*>(rp + 16);  // c = 16+8h..
            acc = __builtin_amdgcn_mfma_f32_32x32x16_f16(a0, bw[2 * m],     acc, 0, 0, 0);
            acc = __builtin_amdgcn_mfma_f32_32x32x16_f16(a1, bw[2 * m + 1], acc, 0, 0, 0);
        }
        // Measured C/D layout (m74/m101): col = lane&31, row = (r&3)+8*(r>>2)+4*(lane>>5)
#pragma unroll
        for (int r = 0; r < 16; ++r) {
            int orow = (r & 3) + 8 * (r >> 2) + 4 * h;
            out[((size_t)(bbase + orow) * F_ + f) * O_ + r32] = acc[r] + bias;
        }
    }
}

// ---------------- Fallback (correct, slow) if ws too small ----------------
__global__ __launch_bounds__(256) void fallback_kernel(
    const float* __restrict__ x, const int* __restrict__ mask,
    const float* __restrict__ coeffs, const float* __restrict__ biases,
    float* __restrict__ out)
{
    int gid = blockIdx.x * 256 + threadIdx.x;   // over B*F*O
    int o = gid & (O_ - 1);
    int f = (gid >> 5) & (F_ - 1);
    int b = gid >> 17;
    float acc = biases[f * O_ + o];
    for (int m = 0; m < M_; ++m) {
        int s = mask[m * F_ + f];
        const float* xr = x + ((size_t)b * F_ + s) * C_;
        const float* wr = coeffs + (m * C_) * O_ + o;
#pragma unroll
        for (int c = 0; c < C_; ++c)
            acc += xr[c] * wr[c * O_];
    }
    out[gid] = acc;
}

extern "C" void kernel_launch(void* const* d_in, const int* in_sizes, int n_in,
                              void* d_out, int out_size, void* d_ws, size_t ws_size,
                              hipStream_t stream) {
    const float* x      = (const float*)d_in[0];
    const int*   mask   = (const int*)d_in[1];
    const float* coeffs = (const float*)d_in[2];
    const float* biases = (const float*)d_in[3];
    float* out = (float*)d_out;

    const size_t xh_elems = (size_t)B_ * F_ * C_;
    const size_t need = xh_elems * sizeof(_Float16) + (size_t)T_ * 64 * 8 * sizeof(_Float16);

    if (ws_size >= need) {
        _Float16* xh = (_Float16*)d_ws;
        _Float16* wf = xh + xh_elems;
        pass1_convert<<<(B_ * F_ * C_) / (8 * 256), 256, 0, stream>>>(x, coeffs, xh, wf);
        pass2_gemm<<<F_ / FPB, 256, 0, stream>>>(xh, wf, mask, biases, out);
    } else {
        fallback_kernel<<<(B_ * F_ * O_) / 256, 256, 0, stream>>>(x, mask, coeffs, biases, out);
    }
}

// Round 2
// 177.535 us; speedup vs baseline: 1.1146x; 1.1146x over previous
//
#include <hip/hip_runtime.h>

// ConvByMoveLayer: out[b,f,o] = sum_m sum_c x[b, mask[m,f], c] * W[m,c,o] + bias[f,o]
// B=128, F=4096, C=32, O=32, M=9.
//
// Round 2: field-major gather layout.
//   Pass 1: transpose+convert x[b][f][c] fp32 -> xh[f][b][c] fp16 (96+64 MB stream);
//           block 0 also builds Wstack in MFMA B-fragment order.
//   Pass 2: gather per (move, field) is now one contiguous 8 KB run per block
//           (2 KB per wave) instead of 32 lines scattered 256 KB apart.
//           Wave = 32 batches x 1 field, 18x v_mfma_f32_32x32x16_f16 (K=288).

#define B_ 128
#define F_ 4096
#define C_ 32
#define O_ 32
#define M_ 9
#define T_ 18   // K=16 MFMA slices (M_*C_/16)
#define FPB 4   // fields per block (pass 2)

typedef _Float16 halfx8 __attribute__((ext_vector_type(8)));
typedef float floatx16 __attribute__((ext_vector_type(16)));

// ---------------- Pass 1: transpose + convert, build W fragments ----------------
__global__ __launch_bounds__(256) void pass1_transpose(
    const float* __restrict__ x, const float* __restrict__ coeffs,
    _Float16* __restrict__ xh, _Float16* __restrict__ wf)
{
    const int gid  = blockIdx.x * 256 + threadIdx.x;
    const int lane = gid & 63;
    const int wid  = gid >> 6;              // 0..8191
    const int b    = wid >> 6;              // 0..127
    const int f    = (wid & 63) * 64 + lane;

    // Read one (b,f) row: 32 fp32 = 128 B contiguous per lane; wave = 8 KB run.
    const float4* src = reinterpret_cast<const float4*>(x + ((size_t)b * F_ + f) * C_);
    float4 v[8];
#pragma unroll
    for (int j = 0; j < 8; ++j) v[j] = src[j];

    // Write to xh[f][b][c]: 64 B per lane at 8 KB stride (full-line writes).
    _Float16* dst = xh + ((size_t)f * B_ + b) * C_;
#pragma unroll
    for (int j = 0; j < 4; ++j) {
        halfx8 t;
        t[0] = (_Float16)v[2 * j].x;     t[1] = (_Float16)v[2 * j].y;
        t[2] = (_Float16)v[2 * j].z;     t[3] = (_Float16)v[2 * j].w;
        t[4] = (_Float16)v[2 * j + 1].x; t[5] = (_Float16)v[2 * j + 1].y;
        t[6] = (_Float16)v[2 * j + 1].z; t[7] = (_Float16)v[2 * j + 1].w;
        *reinterpret_cast<halfx8*>(dst + j * 8) = t;
    }

    // Block 0 builds the B-fragment-ordered weight stack:
    // wf[t][lane][j] = W[m = t>>1][c = 16*(t&1) + 8*(lane>>5) + j][o = lane&31]
    if (blockIdx.x == 0) {
        for (int id = threadIdx.x; id < T_ * 64; id += 256) {
            int t  = id >> 6;
            int L  = id & 63;
            int m  = t >> 1;
            int cb = 16 * (t & 1) + 8 * (L >> 5);
            int o  = L & 31;
            halfx8 w;
#pragma unroll
            for (int j = 0; j < 8; ++j)
                w[j] = (_Float16)coeffs[(m * C_ + cb + j) * O_ + o];
            *reinterpret_cast<halfx8*>(wf + id * 8) = w;
        }
    }
}

// ---------------- Pass 2: gather + MFMA GEMM ----------------
__global__ __launch_bounds__(256) void pass2_gemm(
    const _Float16* __restrict__ xh, const _Float16* __restrict__ wf,
    const int* __restrict__ mask, const float* __restrict__ biases,
    float* __restrict__ out)
{
    __shared__ int smask[M_][FPB];
    const int f0  = blockIdx.x * FPB;
    const int tid = threadIdx.x;
    if (tid < M_ * FPB) {
        int m  = tid / FPB;
        int fi = tid % FPB;
        smask[m][fi] = mask[m * F_ + f0 + fi];
    }
    __syncthreads();

    const int lane  = tid & 63;
    const int wave  = tid >> 6;     // 0..3 -> batch quarter
    const int r32   = lane & 31;
    const int h     = lane >> 5;    // K-half selector for A/B fragments
    const int bbase = wave * 32;

    // Load all 18 B-fragments once per wave (hot 18 KB, L2-resident).
    halfx8 bw[T_];
    const halfx8* wfv = reinterpret_cast<const halfx8*>(wf);
#pragma unroll
    for (int t = 0; t < T_; ++t) bw[t] = wfv[t * 64 + lane];

    // A-fragment base in field-major layout: xh[s][b][c], s-stride = B_*C_.
    // Lane reads 16 B at (bbase+r32)*64B + 16*h B -> wave covers a 2 KB run.
    const _Float16* xbase = xh + (size_t)(bbase + r32) * C_ + 8 * h;

    for (int fi = 0; fi < FPB; ++fi) {
        const int f = f0 + fi;
        floatx16 acc;
#pragma unroll
        for (int i = 0; i < 16; ++i) acc[i] = 0.0f;
        float bias = biases[f * O_ + r32];
#pragma unroll
        for (int m = 0; m < M_; ++m) {
            const _Float16* rp = xbase + (size_t)smask[m][fi] * (B_ * C_);
            halfx8 a0 = *reinterpret_cast<const halfx8*>(rp);       // c = 8h..8h+7
            halfx8 a1 = *reinterpret_cast<const halfx8*>(rp + 16);  // c = 16+8h..
            acc = __builtin_amdgcn_mfma_f32_32x32x16_f16(a0, bw[2 * m],     acc, 0, 0, 0);
            acc = __builtin_amdgcn_mfma_f32_32x32x16_f16(a1, bw[2 * m + 1], acc, 0, 0, 0);
        }
        // Measured C/D layout (m74/m101): col = lane&31, row = (r&3)+8*(r>>2)+4*(lane>>5)
#pragma unroll
        for (int r = 0; r < 16; ++r) {
            int orow = (r & 3) + 8 * (r >> 2) + 4 * h;
            out[((size_t)(bbase + orow) * F_ + f) * O_ + r32] = acc[r] + bias;
        }
    }
}

// ---------------- Fallback (correct, slow) if ws too small ----------------
__global__ __launch_bounds__(256) void fallback_kernel(
    const float* __restrict__ x, const int* __restrict__ mask,
    const float* __restrict__ coeffs, const float* __restrict__ biases,
    float* __restrict__ out)
{
    int gid = blockIdx.x * 256 + threadIdx.x;   // over B*F*O
    int o = gid & (O_ - 1);
    int f = (gid >> 5) & (F_ - 1);
    int b = gid >> 17;
    float acc = biases[f * O_ + o];
    for (int m = 0; m < M_; ++m) {
        int s = mask[m * F_ + f];
        const float* xr = x + ((size_t)b * F_ + s) * C_;
        const float* wr = coeffs + (m * C_) * O_ + o;
#pragma unroll
        for (int c = 0; c < C_; ++c)
            acc += xr[c] * wr[c * O_];
    }
    out[gid] = acc;
}

extern "C" void kernel_launch(void* const* d_in, const int* in_sizes, int n_in,
                              void* d_out, int out_size, void* d_ws, size_t ws_size,
                              hipStream_t stream) {
    const float* x      = (const float*)d_in[0];
    const int*   mask   = (const int*)d_in[1];
    const float* coeffs = (const float*)d_in[2];
    const float* biases = (const float*)d_in[3];
    float* out = (float*)d_out;

    const size_t xh_elems = (size_t)B_ * F_ * C_;
    const size_t need = xh_elems * sizeof(_Float16) + (size_t)T_ * 64 * 8 * sizeof(_Float16);

    if (ws_size >= need) {
        _Float16* xh = (_Float16*)d_ws;
        _Float16* wf = xh + xh_elems;
        pass1_transpose<<<(B_ * F_) / (64 * 4), 256, 0, stream>>>(x, coeffs, xh, wf);
        pass2_gemm<<<F_ / FPB, 256, 0, stream>>>(xh, wf, mask, biases, out);
    } else {
        fallback_kernel<<<(B_ * F_ * O_) / 256, 256, 0, stream>>>(x, mask, coeffs, biases, out);
    }
}

// Round 3
// 164.000 us; speedup vs baseline: 1.2066x; 1.0825x over previous
//
#include <hip/hip_runtime.h>

// ConvByMoveLayer: out[b,f,o] = sum_m sum_c x[b, mask[m,f], c] * W[m,c,o] + bias[f,o]
// B=128, F=4096, C=32, O=32, M=9.
//
// Round 3: latency-bound fixes.
//   Pass 1: LDS-tiled transpose x[b][f][c] fp32 -> xh[f][b][c] fp16.
//           Reads 2 KB runs, writes 1 KB runs (no 64B-at-8KB-stride RMW).
//   Pass 2: weights staged in LDS (frees VGPRs), 18 gather loads in flight
//           per wave, __launch_bounds__(256,4). FPB=2 -> 2048 blocks.

#define B_ 128
#define F_ 4096
#define C_ 32
#define O_ 32
#define M_ 9
#define T_ 18         // K=16 MFMA slices (M_*C_/16)
#define FPB 2         // fields per block (pass 2)
#define TF 16         // fields per transpose tile
#define TB 32         // batches per transpose tile
#define LROW (TB * C_ + 8)   // padded LDS row (elements)

typedef _Float16 halfx4 __attribute__((ext_vector_type(4)));
typedef _Float16 halfx8 __attribute__((ext_vector_type(8)));
typedef float floatx16 __attribute__((ext_vector_type(16)));

// ---------------- Pass 1: LDS-tiled transpose + convert, build W fragments ----------------
__global__ __launch_bounds__(256) void pass1_transpose(
    const float* __restrict__ x, const float* __restrict__ coeffs,
    _Float16* __restrict__ xh, _Float16* __restrict__ wf)
{
    __shared__ _Float16 tile[TF * LROW];
    const int tid  = threadIdx.x;
    const int f0   = blockIdx.x * TF;
    const int b0   = blockIdx.y * TB;
    const int tsub = tid & 127;
    const int grp  = tid >> 7;          // 0/1: two 128-thread groups

    // Read phase: group covers 2 KB contiguous (16 f x 32 c fp32) per b.
    {
        const int f_l = tsub >> 3;
        const int c4  = (tsub & 7) * 4;
#pragma unroll
        for (int it = 0; it < TB / 2; ++it) {
            int b_l = it * 2 + grp;
            float4 v = *reinterpret_cast<const float4*>(
                x + ((size_t)(b0 + b_l) * F_ + f0 + f_l) * C_ + c4);
            halfx4 hv;
            hv[0] = (_Float16)v.x; hv[1] = (_Float16)v.y;
            hv[2] = (_Float16)v.z; hv[3] = (_Float16)v.w;
            *reinterpret_cast<halfx4*>(&tile[f_l * LROW + b_l * C_ + c4]) = hv;
        }
    }
    __syncthreads();

    // Write phase: per field, 32 b x 32 c fp16 = 2 KB contiguous run.
    {
        const int b_l = tsub >> 2;
        const int c8  = (tsub & 3) * 8;
#pragma unroll
        for (int it = 0; it < TF / 2; ++it) {
            int f_l = it * 2 + grp;
            halfx8 v = *reinterpret_cast<const halfx8*>(&tile[f_l * LROW + b_l * C_ + c8]);
            *reinterpret_cast<halfx8*>(
                xh + ((size_t)(f0 + f_l) * B_ + b0 + b_l) * C_ + c8) = v;
        }
    }

    // Block (0,0) builds the B-fragment-ordered weight stack:
    // wf[t][lane][j] = W[m = t>>1][c = 16*(t&1) + 8*(lane>>5) + j][o = lane&31]
    if (blockIdx.x == 0 && blockIdx.y == 0) {
        for (int id = threadIdx.x; id < T_ * 64; id += 256) {
            int t  = id >> 6;
            int L  = id & 63;
            int m  = t >> 1;
            int cb = 16 * (t & 1) + 8 * (L >> 5);
            int o  = L & 31;
            halfx8 w;
#pragma unroll
            for (int j = 0; j < 8; ++j)
                w[j] = (_Float16)coeffs[(m * C_ + cb + j) * O_ + o];
            *reinterpret_cast<halfx8*>(wf + id * 8) = w;
        }
    }
}

// ---------------- Pass 2: gather + MFMA GEMM (weights in LDS) ----------------
__global__ __launch_bounds__(256, 4) void pass2_gemm(
    const _Float16* __restrict__ xh, const _Float16* __restrict__ wf,
    const int* __restrict__ mask, const float* __restrict__ biases,
    float* __restrict__ out)
{
    __shared__ _Float16 sw[T_ * 64 * 8];   // 18 KB: B-fragments for all 18 K-slices
    const int tid = threadIdx.x;
#pragma unroll
    for (int i = tid; i < T_ * 64; i += 256)
        *reinterpret_cast<halfx8*>(&sw[i * 8]) = reinterpret_cast<const halfx8*>(wf)[i];
    __syncthreads();

    const int lane  = tid & 63;
    const int wave  = tid >> 6;     // batch quarter
    const int r32   = lane & 31;
    const int h     = lane >> 5;    // K-half selector
    const int bbase = wave * 32;
    const int f0    = blockIdx.x * FPB;

    // A base in field-major layout xh[s][b][c]; wave covers a 2 KB run per slice pair.
    const _Float16* xbase = xh + (size_t)(bbase + r32) * C_ + 8 * h;

    for (int fi = 0; fi < FPB; ++fi) {
        const int f = f0 + fi;
        // Issue all 18 gather loads up front (mask[..] is block-uniform -> s_load).
        halfx8 a[T_];
#pragma unroll
        for (int m = 0; m < M_; ++m) {
            const _Float16* rp = xbase + (size_t)mask[m * F_ + f] * (B_ * C_);
            a[2 * m]     = *reinterpret_cast<const halfx8*>(rp);       // c = 8h..8h+7
            a[2 * m + 1] = *reinterpret_cast<const halfx8*>(rp + 16);  // c = 16+8h..
        }
        floatx16 acc;
#pragma unroll
        for (int i = 0; i < 16; ++i) acc[i] = 0.0f;
#pragma unroll
        for (int t = 0; t < T_; ++t) {
            halfx8 bwt = *reinterpret_cast<const halfx8*>(&sw[(t * 64 + lane) * 8]);
            acc = __builtin_amdgcn_mfma_f32_32x32x16_f16(a[t], bwt, acc, 0, 0, 0);
        }
        float bias = biases[f * O_ + r32];
        // Measured C/D layout (m74/m101): col = lane&31, row = (r&3)+8*(r>>2)+4*(lane>>5)
#pragma unroll
        for (int r = 0; r < 16; ++r) {
            int orow = (r & 3) + 8 * (r >> 2) + 4 * h;
            out[((size_t)(bbase + orow) * F_ + f) * O_ + r32] = acc[r] + bias;
        }
    }
}

// ---------------- Fallback (correct, slow) if ws too small ----------------
__global__ __launch_bounds__(256) void fallback_kernel(
    const float* __restrict__ x, const int* __restrict__ mask,
    const float* __restrict__ coeffs, const float* __restrict__ biases,
    float* __restrict__ out)
{
    int gid = blockIdx.x * 256 + threadIdx.x;   // over B*F*O
    int o = gid & (O_ - 1);
    int f = (gid >> 5) & (F_ - 1);
    int b = gid >> 17;
    float acc = biases[f * O_ + o];
    for (int m = 0; m < M_; ++m) {
        int s = mask[m * F_ + f];
        const float* xr = x + ((size_t)b * F_ + s) * C_;
        const float* wr = coeffs + (m * C_) * O_ + o;
#pragma unroll
        for (int c = 0; c < C_; ++c)
            acc += xr[c] * wr[c * O_];
    }
    out[gid] = acc;
}

extern "C" void kernel_launch(void* const* d_in, const int* in_sizes, int n_in,
                              void* d_out, int out_size, void* d_ws, size_t ws_size,
                              hipStream_t stream) {
    const float* x      = (const float*)d_in[0];
    const int*   mask   = (const int*)d_in[1];
    const float* coeffs = (const float*)d_in[2];
    const float* biases = (const float*)d_in[3];
    float* out = (float*)d_out;

    const size_t xh_elems = (size_t)B_ * F_ * C_;
    const size_t need = xh_elems * sizeof(_Float16) + (size_t)T_ * 64 * 8 * sizeof(_Float16);

    if (ws_size >= need) {
        _Float16* xh = (_Float16*)d_ws;
        _Float16* wf = xh + xh_elems;
        dim3 g1(F_ / TF, B_ / TB);
        pass1_transpose<<<g1, 256, 0, stream>>>(x, coeffs, xh, wf);
        pass2_gemm<<<F_ / FPB, 256, 0, stream>>>(xh, wf, mask, biases, out);
    } else {
        fallback_kernel<<<(B_ * F_ * O_) / 256, 256, 0, stream>>>(x, mask, coeffs, biases, out);
    }
}

// Round 5
// 143.529 us; speedup vs baseline: 1.3787x; 1.1426x over previous
//
#include <hip/hip_runtime.h>

// ConvByMoveLayer: out[b,f,o] = sum_m sum_c x[b, mask[m,f], c] * W[m,c,o] + bias[f,o]
// B=128, F=4096, C=32, O=32, M=9.
//
// Round 5: XCD-local gather (round 4 retry; fixed nontemporal-load pointer type).
//   xh2[bslice][f][b'][c] fp16: 8 slices x 16 batches = 4 MB/slice = one XCD's L2.
//   Blocks with blk%8==j handle slice j only (round-robin block->XCD dispatch),
//   so the 9x gather re-read hits the XCD's own L2 instead of the 3.5 TB/s
//   L2-miss path that pinned rounds 1-3. Wave tile = 2 fields x 16 batches
//   (weights are field-independent, so MFMA rows can mix fields).
//   out stores are nontemporal (don't evict the slice from L2); pass1 x reads
//   are nontemporal; pass1 writes slice j from blocks blk%8==j (warm L2).

#define B_ 128
#define F_ 4096
#define C_ 32
#define O_ 32
#define M_ 9
#define T_ 18          // K=16 MFMA slices (M_*C_/16)
#define TF1 32         // fields per pass1 block
#define LROW1 528      // padded LDS row (halfs): 16*32 + 16 -> uniform 2-way banks (free)

typedef _Float16 halfx4 __attribute__((ext_vector_type(4)));
typedef _Float16 halfx8 __attribute__((ext_vector_type(8)));
typedef float floatx4 __attribute__((ext_vector_type(4)));
typedef float floatx16 __attribute__((ext_vector_type(16)));

// ---------------- Pass 1: slice-transpose + convert, build W fragments ----------------
// grid: 8 * (F_/TF1) blocks; blk%8 = bslice (XCD), blk/8 = field tile.
__global__ __launch_bounds__(256) void pass1_transpose(
    const float* __restrict__ x, const float* __restrict__ coeffs,
    _Float16* __restrict__ xh, _Float16* __restrict__ wf)
{
    __shared__ _Float16 tile[TF1 * LROW1];
    const int blk = blockIdx.x;
    const int bs  = blk & 7;
    const int f0  = (blk >> 3) * TF1;
    const int tid = threadIdx.x;

    // Read phase: 16 iters over b' ; wave covers 1 KB contiguous (8 f x 32 c fp32).
    {
        const int f_l = tid >> 3;
        const int c4  = (tid & 7) * 4;
        const float* src = x + ((size_t)f0 + f_l) * C_ + c4;
#pragma unroll
        for (int bp = 0; bp < 16; ++bp) {
            const floatx4* p = reinterpret_cast<const floatx4*>(
                src + (size_t)(bs * 16 + bp) * (F_ * C_));
            floatx4 v = __builtin_nontemporal_load(p);
            halfx4 hv;
            hv[0] = (_Float16)v[0]; hv[1] = (_Float16)v[1];
            hv[2] = (_Float16)v[2]; hv[3] = (_Float16)v[3];
            *reinterpret_cast<halfx4*>(&tile[f_l * LROW1 + bp * C_ + c4]) = hv;
        }
    }
    __syncthreads();

    // Write phase: per field, 16 b' x 32 c fp16 = 1 KB contiguous per wave.
    {
        const int wv   = tid >> 6;
        const int lane = tid & 63;
#pragma unroll
        for (int it = 0; it < TF1 / 4; ++it) {
            int f_l = it * 4 + wv;
            halfx8 v = *reinterpret_cast<const halfx8*>(&tile[f_l * LROW1 + lane * 8]);
            *reinterpret_cast<halfx8*>(
                xh + ((size_t)bs * F_ + f0 + f_l) * (16 * C_) + lane * 8) = v;
        }
    }

    // Block 0 builds the B-fragment-ordered weight stack:
    // wf[t][lane][j] = W[m = t>>1][c = 16*(t&1) + 8*(lane>>5) + j][o = lane&31]
    if (blk == 0) {
        for (int id = tid; id < T_ * 64; id += 256) {
            int t  = id >> 6;
            int L  = id & 63;
            int m  = t >> 1;
            int cb = 16 * (t & 1) + 8 * (L >> 5);
            int o  = L & 31;
            halfx8 w;
#pragma unroll
            for (int j = 0; j < 8; ++j)
                w[j] = (_Float16)coeffs[(m * C_ + cb + j) * O_ + o];
            *reinterpret_cast<halfx8*>(wf + id * 8) = w;
        }
    }
}

// ---------------- Pass 2: XCD-local gather + MFMA GEMM ----------------
// grid: 8 * (F_/8) blocks; blk%8 = bslice (XCD), blk/8 = field group of 8.
// Wave tile: 32 rows = 2 fields x 16 batches; 18x v_mfma_f32_32x32x16_f16 (K=288).
__global__ __launch_bounds__(256, 4) void pass2_gemm(
    const _Float16* __restrict__ xh, const _Float16* __restrict__ wf,
    const int* __restrict__ mask, const float* __restrict__ biases,
    float* __restrict__ out)
{
    __shared__ _Float16 sw[T_ * 64 * 8];   // 18 KB B-fragments
    const int tid = threadIdx.x;
#pragma unroll
    for (int i = tid; i < T_ * 64; i += 256)
        reinterpret_cast<halfx8*>(sw)[i] = reinterpret_cast<const halfx8*>(wf)[i];
    __syncthreads();

    const int blk  = blockIdx.x;
    const int bs   = blk & 7;                // batch slice == XCD (round-robin)
    const int fg   = blk >> 3;               // field group (8 fields)
    const int wave = tid >> 6;
    const int lane = tid & 63;
    const int h    = lane >> 5;              // K-half selector
    const int row  = lane & 31;              // MFMA M-row = fi*16 + b'
    const int fi   = row >> 4;
    const int bp   = row & 15;
    const int ocol = lane & 31;              // C/D col = output channel

    const int fa = fg * 8 + 2 * wave;        // this wave's field pair {fa, fa+1}
    const int f  = fa + fi;                  // per-lane field

    // Slice base: xh2[bs][s][b'][c], s-stride = 16*C_ halfs.
    const _Float16* xb = xh + (size_t)bs * F_ * (16 * C_) + bp * C_ + 8 * h;

    // Gather indices (2 distinct values per wave -> cheap vector loads).
    int sidx[M_];
#pragma unroll
    for (int m = 0; m < M_; ++m) sidx[m] = mask[m * F_ + f];

    // All 18 gather loads; each hits this XCD's L2-resident 4 MB slice.
    halfx8 a[T_];
#pragma unroll
    for (int m = 0; m < M_; ++m) {
        const _Float16* rp = xb + (size_t)sidx[m] * (16 * C_);
        a[2 * m]     = *reinterpret_cast<const halfx8*>(rp);       // c = 8h..8h+7
        a[2 * m + 1] = *reinterpret_cast<const halfx8*>(rp + 16);  // c = 16+8h..
    }

    floatx16 acc;
#pragma unroll
    for (int i = 0; i < 16; ++i) acc[i] = 0.0f;
#pragma unroll
    for (int t = 0; t < T_; ++t) {
        halfx8 bwt = *reinterpret_cast<const halfx8*>(&sw[(t * 64 + lane) * 8]);
        acc = __builtin_amdgcn_mfma_f32_32x32x16_f16(a[t], bwt, acc, 0, 0, 0);
    }

    float bias_a = biases[(size_t)fa * O_ + ocol];
    float bias_b = biases[(size_t)(fa + 1) * O_ + ocol];
    // C/D layout (m74/m101): col = lane&31, row = (r&3)+8*(r>>2)+4*(lane>>5)
#pragma unroll
    for (int r = 0; r < 16; ++r) {
        int orow = (r & 3) + 8 * (r >> 2) + 4 * h;
        int ofi  = orow >> 4;
        int b    = bs * 16 + (orow & 15);
        float v  = acc[r] + (ofi ? bias_b : bias_a);
        __builtin_nontemporal_store(
            v, &out[((size_t)b * F_ + fa + ofi) * O_ + ocol]);
    }
}

// ---------------- Fallback (correct, slow) if ws too small ----------------
__global__ __launch_bounds__(256) void fallback_kernel(
    const float* __restrict__ x, const int* __restrict__ mask,
    const float* __restrict__ coeffs, const float* __restrict__ biases,
    float* __restrict__ out)
{
    int gid = blockIdx.x * 256 + threadIdx.x;   // over B*F*O
    int o = gid & (O_ - 1);
    int f = (gid >> 5) & (F_ - 1);
    int b = gid >> 17;
    float acc = biases[f * O_ + o];
    for (int m = 0; m < M_; ++m) {
        int s = mask[m * F_ + f];
        const float* xr = x + ((size_t)b * F_ + s) * C_;
        const float* wr = coeffs + (m * C_) * O_ + o;
#pragma unroll
        for (int c = 0; c < C_; ++c)
            acc += xr[c] * wr[c * O_];
    }
    out[gid] = acc;
}

extern "C" void kernel_launch(void* const* d_in, const int* in_sizes, int n_in,
                              void* d_out, int out_size, void* d_ws, size_t ws_size,
                              hipStream_t stream) {
    const float* x      = (const float*)d_in[0];
    const int*   mask   = (const int*)d_in[1];
    const float* coeffs = (const float*)d_in[2];
    const float* biases = (const float*)d_in[3];
    float* out = (float*)d_out;

    const size_t xh_elems = (size_t)B_ * F_ * C_;
    const size_t need = xh_elems * sizeof(_Float16) + (size_t)T_ * 64 * 8 * sizeof(_Float16);

    if (ws_size >= need) {
        _Float16* xh = (_Float16*)d_ws;
        _Float16* wf = xh + xh_elems;
        pass1_transpose<<<8 * (F_ / TF1), 256, 0, stream>>>(x, coeffs, xh, wf);
        pass2_gemm<<<8 * (F_ / 8), 256, 0, stream>>>(xh, wf, mask, biases, out);
    } else {
        fallback_kernel<<<(B_ * F_ * O_) / 256, 256, 0, stream>>>(x, mask, coeffs, biases, out);
    }
}